// Round 3
// baseline (1383.627 us; speedup 1.0000x reference)
//
#include <hip/hip_runtime.h>
#include <cmath>

// ---------------------------------------------------------------------------
// g_s: 4x chained conv_transpose2d(k=5,s=2,p=2,op=1) + integer quant epilogue.
// Hermite: sum_j floor((round(w)+j)/split) == round(w) -> one conv per layer.
// Exact i8 formulation: weights round(w) in [-127,127]; activations in [0,255]
// stored as (x-128) in i8; OOB halo staged as -128 so
//   conv_i8 = conv_ref(x) - 128 * sum_all_taps(w)   (position-independent!)
// => epilogue adds 128*tapsum[parity][co], exact i32, then the fp32 quant ops.
// MFMA: v_mfma_i32_32x32x32_i8 (1.85x f16 rate, K=32 per 16B fragment).
// ---------------------------------------------------------------------------

typedef int int4v  __attribute__((ext_vector_type(4)));
typedef int int16v __attribute__((ext_vector_type(16)));

// tap id -> (ky,kx). Taps 0-8: EE; 9-14: EO; 15-20: OE; 21-24: OO.
__device__ __forceinline__ void tap_to_k(int t, int& ky, int& kx) {
    if (t < 9)       { int dy = t/3,  dx = t%3;                   ky = 4-2*dy; kx = 4-2*dx; }
    else if (t < 15) { int u = t-9;   int dy = u/2, dx = 1+(u&1);  ky = 4-2*dy; kx = 5-2*dx; }
    else if (t < 21) { int u = t-15;  int dy = 1+u/3, dx = u%3;    ky = 5-2*dy; kx = 4-2*dx; }
    else             { int u = t-21;  int dy = 1+u/2, dx = 1+(u&1); ky = 5-2*dy; kx = 5-2*dx; }
}

// f32 NCHW -> i8 (x-128) NHWC  (layer-1 input)
__global__ void convert_x(const float* __restrict__ x, signed char* __restrict__ xh,
                          int C, int HW) {
    int idx = blockIdx.x * blockDim.x + threadIdx.x;
    if (idx >= C * HW) return;
    int ci = idx % C;
    int p  = idx / C;
    xh[idx] = (signed char)((int)x[(size_t)ci * HW + p] - 128);
}

// torch [Cin][Cout][5][5] f32 -> i8 B-fragment order:
// byte addr = ((qs*NT + nb)*25 + t)*1024 + lane*16 + j
// value = clamp(round(w[ci = qs*32 + (lane>>5)*16 + j][co = nb*32 + (lane&31)]))
__global__ void pack_w_i8(const float* __restrict__ w, signed char* __restrict__ wpk,
                          int Cout, int NT, int KS) {
    int idx = blockIdx.x * blockDim.x + threadIdx.x;
    int total = KS * NT * 25 * 1024;
    if (idx >= total) return;
    int j    = idx & 15;
    int lane = (idx >> 4) & 63;
    int rem  = idx >> 10;
    int t    = rem % 25;  rem /= 25;
    int nb   = rem % NT;
    int qs   = rem / NT;
    int ci = qs * 32 + ((lane >> 5) << 4) + j;
    int co = nb * 32 + (lane & 31);
    int ky, kx; tap_to_k(t, ky, kx);
    float v = 0.0f;
    if (co < Cout) {
        v = rintf(w[(size_t)(ci * Cout + co) * 25 + ky * 5 + kx]);
        v = fminf(fmaxf(v, -128.0f), 127.0f);
    }
    wpk[idx] = (signed char)(int)v;
}

// tapsum[p][co] = sum_{ky%2==py, kx%2==px} sum_ci round(w)   (i32, p = py*2+px)
__global__ void tap_sums(const float* __restrict__ w, int* __restrict__ ts,
                         int Cin, int Cout) {
    int i = blockIdx.x * blockDim.x + threadIdx.x;
    if (i >= 4 * Cout) return;
    int co = i % Cout, p = i / Cout;
    int py = p >> 1, px = p & 1;
    int s = 0;
    for (int ky = py; ky < 5; ky += 2)
        for (int kx = px; kx < 5; kx += 2)
            for (int ci = 0; ci < Cin; ++ci) {
                float v = rintf(w[(size_t)(ci * Cout + co) * 25 + ky * 5 + kx]);
                v = fminf(fmaxf(v, -128.0f), 127.0f);
                s += (int)v;
            }
    ts[i] = s;
}

// Block: 4 waves (MW=4, NW=1 -> all share co-tile), R=2 m-subtiles/wave.
// Tile = 16x16 quads (32x32 outputs) x 32 co x 4 parities.
// xs layout: plane g (16B of ci) x 324 pixels: addr = (g*324 + p)*16.
template<int KC, bool FINAL>
__global__ __launch_bounds__(256, 2)
void deconv_i8(const signed char* __restrict__ xin, const signed char* __restrict__ wpk,
               const float* __restrict__ bias, const float* __restrict__ muls,
               const int* __restrict__ tsum,
               const float* __restrict__ relus, const int* __restrict__ dvds,
               const int* __restrict__ bitsp,
               int layer, int Cin, int Cout, int NT, int Hq, int Wq,
               void* __restrict__ outp) {
    __shared__ __align__(16) signed char xs[324 * KC];

    const int tid  = threadIdx.x;
    const int lane = tid & 63;
    const int wid  = tid >> 6;               // wave id == wm (MW=4)
    const int qx0  = blockIdx.y * 16;
    const int qy0  = blockIdx.z * 16;
    const int nb   = blockIdx.x;
    const int n0   = nb * 32;

    constexpr int R = 2;
    int16v acc[R][4];
    #pragma unroll
    for (int r = 0; r < R; ++r)
        #pragma unroll
        for (int p = 0; p < 4; ++p)
            #pragma unroll
            for (int e = 0; e < 16; ++e) acc[r][p][e] = 0;

    const int half   = lane >> 5;
    const int rowbit = (lane >> 4) & 1;
    const int col    = lane & 15;
    int p0[R];
    #pragma unroll
    for (int r = 0; r < R; ++r)
        p0[r] = (wid * 4 + r * 2 + rowbit) * 18 + col;

    // shift tables (compile-time foldable)
    constexpr int S_NT[9]     = {1,2,2,2,4,4,2,4,4};
    constexpr int S_TAP[9][4] = {
        {0,0,0,0},{1,9,0,0},{2,10,0,0},{3,15,0,0},
        {4,11,16,21},{5,12,17,22},{6,18,0,0},{7,13,19,23},{8,14,20,24}};
    constexpr int S_PAR[9][4] = {
        {0,0,0,0},{0,1,0,0},{0,1,0,0},{0,2,0,0},
        {0,1,2,3},{0,1,2,3},{0,2,0,0},{0,1,2,3},{0,1,2,3}};

    for (int ck = 0; ck < Cin; ck += KC) {
        __syncthreads();
        constexpr int NG = KC / 16;
        for (int i = tid; i < 324 * NG; i += 256) {
            int p = i / NG;
            int g = i - p * NG;
            int rr = p / 18, cc = p - rr * 18;
            int y = qy0 - 1 + rr, x = qx0 - 1 + cc;
            int4v v = {(int)0x80808080, (int)0x80808080, (int)0x80808080, (int)0x80808080};
            if ((unsigned)y < (unsigned)Hq && (unsigned)x < (unsigned)Wq)
                v = *(const int4v*)&xin[((size_t)y * Wq + x) * Cin + ck + g * 16];
            *(int4v*)&xs[(g * 324 + p) * 16] = v;
        }
        __syncthreads();

        for (int qs = 0; qs < KC / 32; ++qs) {
            const signed char* wq =
                wpk + (((size_t)((ck >> 5) + qs) * NT + nb) * 25) * 1024 + (lane << 4);
            const int abase = ((qs * 2 + half) * 324) * 16;

            #pragma unroll
            for (int s9 = 0; s9 < 9; ++s9) {
                const int dy = s9 / 3, dx = s9 % 3;
                int4v a[R];
                #pragma unroll
                for (int r = 0; r < R; ++r)
                    a[r] = *(const int4v*)&xs[abase + (p0[r] + dy * 18 + dx) * 16];
                #pragma unroll
                for (int u = 0; u < 4; ++u) {
                    if (u < S_NT[s9]) {
                        const int t = S_TAP[s9][u];
                        const int p = S_PAR[s9][u];
                        int4v b = *(const int4v*)&wq[t * 1024];
                        #pragma unroll
                        for (int r = 0; r < R; ++r)
                            acc[r][p] = __builtin_amdgcn_mfma_i32_32x32x32_i8(
                                a[r], b, acc[r][p], 0, 0, 0);
                    }
                }
            }
        }
    }

    // ----- quant epilogue (exact fp32 op sequence; pow2 div == mul by inv) ---
    const int dv = dvds[layer];
    const bool qmode = (layer < 3);
    float add1, inv1, clp = 0.f, scl = 0.f, add2 = 0.f, inv2 = 0.f;
    if (qmode) {
        add1 = ldexpf(1.0f, dv - 10);
        inv1 = ldexpf(1.0f, -(dv - 9));
        const float relu = relus[layer];
        const int sk = (layer == 1) ? 4 : 3;
        const float bitsv = ldexpf(1.0f, bitsp[0]) - 1.0f;
        {
            #pragma clang fp contract(off)
            clp = rintf(bitsv / relu * 33554432.0f);
            scl = floorf((relu + ldexpf(1.0f, sk - 1)) * ldexpf(1.0f, -sk));
        }
        add2 = ldexpf(1.0f, 24 - sk);
        inv2 = ldexpf(1.0f, -(25 - sk));
    } else {
        add1 = ldexpf(1.0f, dv - 9);
        inv1 = ldexpf(1.0f, -(dv - 8));
    }

    const int co = n0 + (lane & 31);
    const bool cok = (co < Cout);
    float bq = 0.f, mm = 0.f;
    int fullp[4] = {0, 0, 0, 0};
    if (cok) {
        bq = rintf(bias[co]);
        mm = muls[co];
        #pragma unroll
        for (int p = 0; p < 4; ++p) fullp[p] = tsum[p * Cout + co];
    }

    const int Wout = Wq * 2, Hout = Hq * 2;
    signed char* acto = (signed char*)outp;
    float* fouto = (float*)outp;

    #pragma unroll
    for (int r = 0; r < R; ++r) {
        #pragma unroll
        for (int p = 0; p < 4; ++p) {
            const int py = p >> 1, px = p & 1;
            #pragma unroll
            for (int reg = 0; reg < 16; ++reg) {
                const int mrow = (reg & 3) + 8 * (reg >> 2) + 4 * (lane >> 5);
                const int qy = qy0 + wid * 4 + r * 2 + (mrow >> 4);
                const int qx = qx0 + (mrow & 15);
                const int tot = acc[r][p][reg] + 128 * fullp[p];
                float v = (float)tot;
                {
                    #pragma clang fp contract(off)
                    v = (v + bq) * mm;
                    v = floorf((v + add1) * inv1);
                    if (qmode) {
                        v = fminf(fmaxf(v, 0.0f), clp);
                        v = floorf((v * scl + add2) * inv2);
                    } else {
                        v = v / 255.0f;
                    }
                }
                if (cok) {
                    const int oy = 2 * qy + py, ox = 2 * qx + px;
                    if (!FINAL)
                        acto[((size_t)oy * Wout + ox) * Cout + co] =
                            (signed char)((int)v - 128);
                    else
                        fouto[((size_t)co * Hout + oy) * Wout + ox] = v;
                }
            }
        }
    }
}

extern "C" void kernel_launch(void* const* d_in, const int* in_sizes, int n_in,
                              void* d_out, int out_size, void* d_ws, size_t ws_size,
                              hipStream_t stream) {
    const float* x  = (const float*)d_in[0];
    const float* w1 = (const float*)d_in[1];
    const float* b1 = (const float*)d_in[2];
    const float* w2 = (const float*)d_in[3];
    const float* b2 = (const float*)d_in[4];
    const float* w3 = (const float*)d_in[5];
    const float* b3 = (const float*)d_in[6];
    const float* w4 = (const float*)d_in[7];
    const float* b4 = (const float*)d_in[8];
    const float* m0 = (const float*)d_in[9];
    const float* m1 = (const float*)d_in[10];
    const float* m2 = (const float*)d_in[11];
    const float* m3 = (const float*)d_in[12];
    const float* relus = (const float*)d_in[13];
    const int* dvds = (const int*)d_in[14];
    const int* bitsp = (const int*)d_in[15];

    signed char* wsb = (signed char*)d_ws;
    size_t o = 0;
    signed char* wpk1 = wsb + o; o += (size_t)10 * 6 * 25 * 1024;  // 1,536,000
    signed char* wpk2 = wsb + o; o += (size_t)6 * 6 * 25 * 1024;   //   921,600
    signed char* wpk3 = wsb + o; o += (size_t)6 * 6 * 25 * 1024;
    signed char* wpk4 = wsb + o; o += (size_t)6 * 1 * 25 * 1024;
    int* ts1 = (int*)(wsb + o); o += 4 * 192 * 4;
    int* ts2 = (int*)(wsb + o); o += 4 * 192 * 4;
    int* ts3 = (int*)(wsb + o); o += 4 * 192 * 4;
    int* ts4 = (int*)(wsb + o); o += 4 * 4 * 4;    // 48B, pad to 64
    o = (o + 15) & ~(size_t)15;
    signed char* xh = wsb + o; o += (size_t)48 * 48 * 320;
    signed char* a1 = wsb + o; o += (size_t)96 * 96 * 192;
    signed char* a2 = wsb + o; o += (size_t)192 * 192 * 192;
    signed char* a3 = wsb + o; o += (size_t)384 * 384 * 192;

    convert_x<<<(320 * 48 * 48 + 255) / 256, 256, 0, stream>>>(x, xh, 320, 48 * 48);
    pack_w_i8<<<(10 * 6 * 25 * 1024 + 255) / 256, 256, 0, stream>>>(w1, wpk1, 192, 6, 10);
    pack_w_i8<<<(6 * 6 * 25 * 1024 + 255) / 256, 256, 0, stream>>>(w2, wpk2, 192, 6, 6);
    pack_w_i8<<<(6 * 6 * 25 * 1024 + 255) / 256, 256, 0, stream>>>(w3, wpk3, 192, 6, 6);
    pack_w_i8<<<(6 * 1 * 25 * 1024 + 255) / 256, 256, 0, stream>>>(w4, wpk4, 3, 1, 6);
    tap_sums<<<3, 256, 0, stream>>>(w1, ts1, 320, 192);
    tap_sums<<<3, 256, 0, stream>>>(w2, ts2, 192, 192);
    tap_sums<<<3, 256, 0, stream>>>(w3, ts3, 192, 192);
    tap_sums<<<1, 64, 0, stream>>>(w4, ts4, 192, 3);

    // layer 1: 48x48x320 -> 96x96x192
    deconv_i8<160, false><<<dim3(6, 3, 3), 256, 0, stream>>>(
        xh, wpk1, b1, m0, ts1, relus, dvds, bitsp, 0, 320, 192, 6, 48, 48, a1);
    // layer 2: 96x96x192 -> 192x192x192
    deconv_i8<192, false><<<dim3(6, 6, 6), 256, 0, stream>>>(
        a1, wpk2, b2, m1, ts2, relus, dvds, bitsp, 1, 192, 192, 6, 96, 96, a2);
    // layer 3: 192x192x192 -> 384x384x192
    deconv_i8<192, false><<<dim3(6, 12, 12), 256, 0, stream>>>(
        a2, wpk3, b3, m2, ts3, relus, dvds, bitsp, 2, 192, 192, 6, 192, 192, a3);
    // layer 4: 384x384x192 -> 3x768x768 (final, f32 NCHW, /255)
    deconv_i8<192, true><<<dim3(1, 24, 24), 256, 0, stream>>>(
        a3, wpk4, b4, m3, ts4, relus, dvds, bitsp, 3, 192, 3, 1, 384, 384, (float*)d_out);
}

// Round 4
// 422.326 us; speedup vs baseline: 3.2762x; 3.2762x over previous
//
#include <hip/hip_runtime.h>
#include <cmath>

// ---------------------------------------------------------------------------
// g_s: 4x chained conv_transpose2d(k=5,s=2,p=2,op=1) + integer quant epilogue.
// Hermite: sum_j floor((round(w)+j)/split) == round(w) -> one conv per layer.
// Exact i8 formulation: weights round(w) in [-127,127]; activations in [0,255]
// stored as (x-128) in i8; OOB halo staged as -128 so
//   conv_i8 = conv_ref(x) - 128 * sum_all_taps(w)   (position-independent!)
// => epilogue adds 128*tapsum[parity][co], exact i32, then the fp32 quant ops.
// MFMA: v_mfma_i32_32x32x32_i8 (1.85x f16 rate, K=32 per 16B fragment).
// ---------------------------------------------------------------------------

typedef int int4v  __attribute__((ext_vector_type(4)));
typedef int int16v __attribute__((ext_vector_type(16)));

// tap id -> (ky,kx). Taps 0-8: EE; 9-14: EO; 15-20: OE; 21-24: OO.
__device__ __forceinline__ void tap_to_k(int t, int& ky, int& kx) {
    if (t < 9)       { int dy = t/3,  dx = t%3;                   ky = 4-2*dy; kx = 4-2*dx; }
    else if (t < 15) { int u = t-9;   int dy = u/2, dx = 1+(u&1);  ky = 4-2*dy; kx = 5-2*dx; }
    else if (t < 21) { int u = t-15;  int dy = 1+u/3, dx = u%3;    ky = 5-2*dy; kx = 4-2*dx; }
    else             { int u = t-21;  int dy = 1+u/2, dx = 1+(u&1); ky = 5-2*dy; kx = 5-2*dx; }
}

// f32 NCHW -> i8 (x-128) NHWC  (layer-1 input)
__global__ void convert_x(const float* __restrict__ x, signed char* __restrict__ xh,
                          int C, int HW) {
    int idx = blockIdx.x * blockDim.x + threadIdx.x;
    if (idx >= C * HW) return;
    int ci = idx % C;
    int p  = idx / C;
    xh[idx] = (signed char)((int)x[(size_t)ci * HW + p] - 128);
}

// torch [Cin][Cout][5][5] f32 -> i8 B-fragment order:
// byte addr = ((qs*NT + nb)*25 + t)*1024 + lane*16 + j
// value = clamp(round(w[ci = qs*32 + (lane>>5)*16 + j][co = nb*32 + (lane&31)]))
__global__ void pack_w_i8(const float* __restrict__ w, signed char* __restrict__ wpk,
                          int Cout, int NT, int KS) {
    int idx = blockIdx.x * blockDim.x + threadIdx.x;
    int total = KS * NT * 25 * 1024;
    if (idx >= total) return;
    int j    = idx & 15;
    int lane = (idx >> 4) & 63;
    int rem  = idx >> 10;
    int t    = rem % 25;  rem /= 25;
    int nb   = rem % NT;
    int qs   = rem / NT;
    int ci = qs * 32 + ((lane >> 5) << 4) + j;
    int co = nb * 32 + (lane & 31);
    int ky, kx; tap_to_k(t, ky, kx);
    float v = 0.0f;
    if (co < Cout) {
        v = rintf(w[(size_t)(ci * Cout + co) * 25 + ky * 5 + kx]);
        v = fminf(fmaxf(v, -128.0f), 127.0f);
    }
    wpk[idx] = (signed char)(int)v;
}

// tapsum[p][co] = sum_{ky%2==py, kx%2==px} sum_ci round(w)   (i32, p = py*2+px)
// One 64-thread block per (p,co) pair; wave-shuffle reduction.
__global__ __launch_bounds__(64)
void tap_sums(const float* __restrict__ w, int* __restrict__ ts,
              int Cin, int Cout) {
    const int i  = blockIdx.x;            // p*Cout + co
    const int co = i % Cout, p = i / Cout;
    const int py = p >> 1, px = p & 1;
    const int nky = (5 - py + 1) >> 1;    // #ky taps for this parity (3 or 2)
    const int nkx = (5 - px + 1) >> 1;
    const int ntap = nky * nkx;
    int s = 0;
    for (int idx = threadIdx.x; idx < Cin * ntap; idx += 64) {
        const int ci = idx / ntap;
        const int u  = idx - ci * ntap;
        const int ky = py + 2 * (u / nkx);
        const int kx = px + 2 * (u % nkx);
        float v = rintf(w[(size_t)(ci * Cout + co) * 25 + ky * 5 + kx]);
        v = fminf(fmaxf(v, -128.0f), 127.0f);
        s += (int)v;
    }
    #pragma unroll
    for (int off = 32; off > 0; off >>= 1)
        s += __shfl_down(s, off, 64);
    if (threadIdx.x == 0) ts[i] = s;
}

// Block: 4 waves (MW=4, NW=1 -> all share co-tile), R=2 m-subtiles/wave.
// Tile = 16x16 quads (32x32 outputs) x 32 co x 4 parities.
// xs layout: plane g (16B of ci) x 324 pixels: addr = (g*324 + p)*16.
template<int KC, bool FINAL>
__global__ __launch_bounds__(256, 2)
void deconv_i8(const signed char* __restrict__ xin, const signed char* __restrict__ wpk,
               const float* __restrict__ bias, const float* __restrict__ muls,
               const int* __restrict__ tsum,
               const float* __restrict__ relus, const int* __restrict__ dvds,
               const int* __restrict__ bitsp,
               int layer, int Cin, int Cout, int NT, int Hq, int Wq,
               void* __restrict__ outp) {
    __shared__ __align__(16) signed char xs[324 * KC];

    const int tid  = threadIdx.x;
    const int lane = tid & 63;
    const int wid  = tid >> 6;               // wave id == wm (MW=4)
    const int qx0  = blockIdx.y * 16;
    const int qy0  = blockIdx.z * 16;
    const int nb   = blockIdx.x;
    const int n0   = nb * 32;

    constexpr int R = 2;
    int16v acc[R][4];
    #pragma unroll
    for (int r = 0; r < R; ++r)
        #pragma unroll
        for (int p = 0; p < 4; ++p)
            #pragma unroll
            for (int e = 0; e < 16; ++e) acc[r][p][e] = 0;

    const int half   = lane >> 5;
    const int rowbit = (lane >> 4) & 1;
    const int col    = lane & 15;
    int p0[R];
    #pragma unroll
    for (int r = 0; r < R; ++r)
        p0[r] = (wid * 4 + r * 2 + rowbit) * 18 + col;

    // shift tables (compile-time foldable)
    constexpr int S_NT[9]     = {1,2,2,2,4,4,2,4,4};
    constexpr int S_TAP[9][4] = {
        {0,0,0,0},{1,9,0,0},{2,10,0,0},{3,15,0,0},
        {4,11,16,21},{5,12,17,22},{6,18,0,0},{7,13,19,23},{8,14,20,24}};
    constexpr int S_PAR[9][4] = {
        {0,0,0,0},{0,1,0,0},{0,1,0,0},{0,2,0,0},
        {0,1,2,3},{0,1,2,3},{0,2,0,0},{0,1,2,3},{0,1,2,3}};

    for (int ck = 0; ck < Cin; ck += KC) {
        __syncthreads();
        constexpr int NG = KC / 16;
        for (int i = tid; i < 324 * NG; i += 256) {
            int p = i / NG;
            int g = i - p * NG;
            int rr = p / 18, cc = p - rr * 18;
            int y = qy0 - 1 + rr, x = qx0 - 1 + cc;
            int4v v = {(int)0x80808080, (int)0x80808080, (int)0x80808080, (int)0x80808080};
            if ((unsigned)y < (unsigned)Hq && (unsigned)x < (unsigned)Wq)
                v = *(const int4v*)&xin[((size_t)y * Wq + x) * Cin + ck + g * 16];
            *(int4v*)&xs[(g * 324 + p) * 16] = v;
        }
        __syncthreads();

        for (int qs = 0; qs < KC / 32; ++qs) {
            const signed char* wq =
                wpk + (((size_t)((ck >> 5) + qs) * NT + nb) * 25) * 1024 + (lane << 4);
            const int abase = ((qs * 2 + half) * 324) * 16;

            #pragma unroll
            for (int s9 = 0; s9 < 9; ++s9) {
                const int dy = s9 / 3, dx = s9 % 3;
                int4v a[R];
                #pragma unroll
                for (int r = 0; r < R; ++r)
                    a[r] = *(const int4v*)&xs[abase + (p0[r] + dy * 18 + dx) * 16];
                #pragma unroll
                for (int u = 0; u < 4; ++u) {
                    if (u < S_NT[s9]) {
                        const int t = S_TAP[s9][u];
                        const int p = S_PAR[s9][u];
                        int4v b = *(const int4v*)&wq[t * 1024];
                        #pragma unroll
                        for (int r = 0; r < R; ++r)
                            acc[r][p] = __builtin_amdgcn_mfma_i32_32x32x32_i8(
                                a[r], b, acc[r][p], 0, 0, 0);
                    }
                }
            }
        }
    }

    // ----- quant epilogue (exact fp32 op sequence; pow2 div == mul by inv) ---
    const int dv = dvds[layer];
    const bool qmode = (layer < 3);
    float add1, inv1, clp = 0.f, scl = 0.f, add2 = 0.f, inv2 = 0.f;
    if (qmode) {
        add1 = ldexpf(1.0f, dv - 10);
        inv1 = ldexpf(1.0f, -(dv - 9));
        const float relu = relus[layer];
        const int sk = (layer == 1) ? 4 : 3;
        const float bitsv = ldexpf(1.0f, bitsp[0]) - 1.0f;
        {
            #pragma clang fp contract(off)
            clp = rintf(bitsv / relu * 33554432.0f);
            scl = floorf((relu + ldexpf(1.0f, sk - 1)) * ldexpf(1.0f, -sk));
        }
        add2 = ldexpf(1.0f, 24 - sk);
        inv2 = ldexpf(1.0f, -(25 - sk));
    } else {
        add1 = ldexpf(1.0f, dv - 9);
        inv1 = ldexpf(1.0f, -(dv - 8));
    }

    const int co = n0 + (lane & 31);
    const bool cok = (co < Cout);
    float bq = 0.f, mm = 0.f;
    int fullp[4] = {0, 0, 0, 0};
    if (cok) {
        bq = rintf(bias[co]);
        mm = muls[co];
        #pragma unroll
        for (int p = 0; p < 4; ++p) fullp[p] = tsum[p * Cout + co];
    }

    const int Wout = Wq * 2, Hout = Hq * 2;
    signed char* acto = (signed char*)outp;
    float* fouto = (float*)outp;

    #pragma unroll
    for (int r = 0; r < R; ++r) {
        #pragma unroll
        for (int p = 0; p < 4; ++p) {
            const int py = p >> 1, px = p & 1;
            #pragma unroll
            for (int reg = 0; reg < 16; ++reg) {
                const int mrow = (reg & 3) + 8 * (reg >> 2) + 4 * (lane >> 5);
                const int qy = qy0 + wid * 4 + r * 2 + (mrow >> 4);
                const int qx = qx0 + (mrow & 15);
                const int tot = acc[r][p][reg] + 128 * fullp[p];
                float v = (float)tot;
                {
                    #pragma clang fp contract(off)
                    v = (v + bq) * mm;
                    v = floorf((v + add1) * inv1);
                    if (qmode) {
                        v = fminf(fmaxf(v, 0.0f), clp);
                        v = floorf((v * scl + add2) * inv2);
                    } else {
                        v = v / 255.0f;
                    }
                }
                if (cok) {
                    const int oy = 2 * qy + py, ox = 2 * qx + px;
                    if (!FINAL)
                        acto[((size_t)oy * Wout + ox) * Cout + co] =
                            (signed char)((int)v - 128);
                    else
                        fouto[((size_t)co * Hout + oy) * Wout + ox] = v;
                }
            }
        }
    }
}

extern "C" void kernel_launch(void* const* d_in, const int* in_sizes, int n_in,
                              void* d_out, int out_size, void* d_ws, size_t ws_size,
                              hipStream_t stream) {
    const float* x  = (const float*)d_in[0];
    const float* w1 = (const float*)d_in[1];
    const float* b1 = (const float*)d_in[2];
    const float* w2 = (const float*)d_in[3];
    const float* b2 = (const float*)d_in[4];
    const float* w3 = (const float*)d_in[5];
    const float* b3 = (const float*)d_in[6];
    const float* w4 = (const float*)d_in[7];
    const float* b4 = (const float*)d_in[8];
    const float* m0 = (const float*)d_in[9];
    const float* m1 = (const float*)d_in[10];
    const float* m2 = (const float*)d_in[11];
    const float* m3 = (const float*)d_in[12];
    const float* relus = (const float*)d_in[13];
    const int* dvds = (const int*)d_in[14];
    const int* bitsp = (const int*)d_in[15];

    signed char* wsb = (signed char*)d_ws;
    size_t o = 0;
    signed char* wpk1 = wsb + o; o += (size_t)10 * 6 * 25 * 1024;  // 1,536,000
    signed char* wpk2 = wsb + o; o += (size_t)6 * 6 * 25 * 1024;   //   921,600
    signed char* wpk3 = wsb + o; o += (size_t)6 * 6 * 25 * 1024;
    signed char* wpk4 = wsb + o; o += (size_t)6 * 1 * 25 * 1024;
    int* ts1 = (int*)(wsb + o); o += 4 * 192 * 4;
    int* ts2 = (int*)(wsb + o); o += 4 * 192 * 4;
    int* ts3 = (int*)(wsb + o); o += 4 * 192 * 4;
    int* ts4 = (int*)(wsb + o); o += 4 * 4 * 4;    // 48B, pad to 64
    o = (o + 15) & ~(size_t)15;
    signed char* xh = wsb + o; o += (size_t)48 * 48 * 320;
    signed char* a1 = wsb + o; o += (size_t)96 * 96 * 192;
    signed char* a2 = wsb + o; o += (size_t)192 * 192 * 192;
    signed char* a3 = wsb + o; o += (size_t)384 * 384 * 192;

    convert_x<<<(320 * 48 * 48 + 255) / 256, 256, 0, stream>>>(x, xh, 320, 48 * 48);
    pack_w_i8<<<(10 * 6 * 25 * 1024 + 255) / 256, 256, 0, stream>>>(w1, wpk1, 192, 6, 10);
    pack_w_i8<<<(6 * 6 * 25 * 1024 + 255) / 256, 256, 0, stream>>>(w2, wpk2, 192, 6, 6);
    pack_w_i8<<<(6 * 6 * 25 * 1024 + 255) / 256, 256, 0, stream>>>(w3, wpk3, 192, 6, 6);
    pack_w_i8<<<(6 * 1 * 25 * 1024 + 255) / 256, 256, 0, stream>>>(w4, wpk4, 3, 1, 6);
    tap_sums<<<4 * 192, 64, 0, stream>>>(w1, ts1, 320, 192);
    tap_sums<<<4 * 192, 64, 0, stream>>>(w2, ts2, 192, 192);
    tap_sums<<<4 * 192, 64, 0, stream>>>(w3, ts3, 192, 192);
    tap_sums<<<4 * 3, 64, 0, stream>>>(w4, ts4, 192, 3);

    // layer 1: 48x48x320 -> 96x96x192
    deconv_i8<160, false><<<dim3(6, 3, 3), 256, 0, stream>>>(
        xh, wpk1, b1, m0, ts1, relus, dvds, bitsp, 0, 320, 192, 6, 48, 48, a1);
    // layer 2: 96x96x192 -> 192x192x192
    deconv_i8<192, false><<<dim3(6, 6, 6), 256, 0, stream>>>(
        a1, wpk2, b2, m1, ts2, relus, dvds, bitsp, 1, 192, 192, 6, 96, 96, a2);
    // layer 3: 192x192x192 -> 384x384x192
    deconv_i8<192, false><<<dim3(6, 12, 12), 256, 0, stream>>>(
        a2, wpk3, b3, m2, ts3, relus, dvds, bitsp, 2, 192, 192, 6, 192, 192, a3);
    // layer 4: 384x384x192 -> 3x768x768 (final, f32 NCHW, /255)
    deconv_i8<192, true><<<dim3(1, 24, 24), 256, 0, stream>>>(
        a3, wpk4, b4, m3, ts4, relus, dvds, bitsp, 3, 192, 3, 1, 384, 384, (float*)d_out);
}

// Round 5
// 312.455 us; speedup vs baseline: 4.4282x; 1.3516x over previous
//
#include <hip/hip_runtime.h>
#include <cmath>

// ---------------------------------------------------------------------------
// g_s: 4x chained conv_transpose2d(k=5,s=2,p=2,op=1) + integer quant epilogue.
// Hermite: sum_j floor((round(w)+j)/split) == round(w) -> one conv per layer.
// Exact i8: weights round(w) in [-127,127]; activations (x-128) in i8; OOB
// halo = -128 so conv_i8 = conv_ref(x) - 128*tapsum[parity][co] (exact i32).
// MFMA v_mfma_i32_32x32x32_i8. 8-wave blocks (R=1) for latency hiding.
// Final layer: B's N-dim = (parity,co) pairs -> 1 MFMA per spatial shift.
// ---------------------------------------------------------------------------

typedef int int4v  __attribute__((ext_vector_type(4)));
typedef int int16v __attribute__((ext_vector_type(16)));

// tap id -> (ky,kx). Taps 0-8: EE; 9-14: EO; 15-20: OE; 21-24: OO.
__device__ __forceinline__ void tap_to_k(int t, int& ky, int& kx) {
    if (t < 9)       { int dy = t/3,  dx = t%3;                   ky = 4-2*dy; kx = 4-2*dx; }
    else if (t < 15) { int u = t-9;   int dy = u/2, dx = 1+(u&1);  ky = 4-2*dy; kx = 5-2*dx; }
    else if (t < 21) { int u = t-15;  int dy = 1+u/3, dx = u%3;    ky = 5-2*dy; kx = 4-2*dx; }
    else             { int u = t-21;  int dy = 1+u/2, dx = 1+(u&1); ky = 5-2*dy; kx = 5-2*dx; }
}

// f32 NCHW -> i8 (x-128) NHWC via LDS transpose (both sides coalesced)
__global__ __launch_bounds__(256)
void convert_x_t(const float* __restrict__ x, signed char* __restrict__ xh,
                 int C, int HW) {
    __shared__ float t[64][65];
    const int p0 = blockIdx.x * 64;
    const int c0 = blockIdx.y * 64;
    const int pL = threadIdx.x & 63;
    const int r0 = threadIdx.x >> 6;  // 0..3
    #pragma unroll
    for (int k = 0; k < 16; ++k) {
        int ciL = r0 * 16 + k;
        t[ciL][pL] = x[(size_t)(c0 + ciL) * HW + p0 + pL];
    }
    __syncthreads();
    #pragma unroll
    for (int k = 0; k < 16; ++k) {
        int pL2 = r0 * 16 + k;
        xh[(size_t)(p0 + pL2) * C + c0 + pL] = (signed char)((int)t[pL][pL2] - 128);
    }
}

// torch [Cin][Cout][5][5] f32 -> i8 B-fragment order (layers 1-3):
// byte addr = ((qs*NT + nb)*25 + t)*1024 + lane*16 + j
__global__ void pack_w_i8(const float* __restrict__ w, signed char* __restrict__ wpk,
                          int Cout, int NT, int KS) {
    int idx = blockIdx.x * blockDim.x + threadIdx.x;
    int total = KS * NT * 25 * 1024;
    if (idx >= total) return;
    int j    = idx & 15;
    int lane = (idx >> 4) & 63;
    int rem  = idx >> 10;
    int t    = rem % 25;  rem /= 25;
    int nb   = rem % NT;
    int qs   = rem / NT;
    int ci = qs * 32 + ((lane >> 5) << 4) + j;
    int co = nb * 32 + (lane & 31);
    int ky, kx; tap_to_k(t, ky, kx);
    float v = 0.0f;
    if (co < Cout) {
        v = rintf(w[(size_t)(ci * Cout + co) * 25 + ky * 5 + kx]);
        v = fminf(fmaxf(v, -128.0f), 127.0f);
    }
    wpk[idx] = (signed char)(int)v;
}

// final-layer pack: N-dim = (parity,co): column c = p*8+co (co<3 live).
// byte addr = ((qs*9 + s9)*64 + lane)*16 + j ; value = w[co][ci][tap(s9,p)] or 0
__global__ void pack_w4_i8(const float* __restrict__ w, signed char* __restrict__ wpk) {
    int idx = blockIdx.x * blockDim.x + threadIdx.x;
    if (idx >= 6 * 9 * 64 * 16) return;
    int j    = idx & 15;
    int lane = (idx >> 4) & 63;
    int rem  = idx >> 10;
    int s9   = rem % 9;
    int qs   = rem / 9;
    int col  = lane & 31;
    int co   = col & 7;
    int p    = col >> 3;
    int py = p >> 1, px = p & 1;
    int dy = s9 / 3, dx = s9 % 3;
    int ci = qs * 32 + ((lane >> 5) << 4) + j;
    bool part = (py == 0 || dy >= 1) && (px == 0 || dx >= 1);
    float v = 0.0f;
    if (co < 3 && part) {
        int ky = py ? 5 - 2 * dy : 4 - 2 * dy;
        int kx = px ? 5 - 2 * dx : 4 - 2 * dx;
        v = rintf(w[(size_t)(ci * 3 + co) * 25 + ky * 5 + kx]);
        v = fminf(fmaxf(v, -128.0f), 127.0f);
    }
    wpk[idx] = (signed char)(int)v;
}

// tapsum[p][co] = sum_{ky%2==py, kx%2==px} sum_ci round(w)   (i32)
__global__ __launch_bounds__(64)
void tap_sums(const float* __restrict__ w, int* __restrict__ ts,
              int Cin, int Cout) {
    const int i  = blockIdx.x;            // p*Cout + co
    const int co = i % Cout, p = i / Cout;
    const int py = p >> 1, px = p & 1;
    const int nky = (5 - py + 1) >> 1;
    const int nkx = (5 - px + 1) >> 1;
    const int ntap = nky * nkx;
    int s = 0;
    for (int idx = threadIdx.x; idx < Cin * ntap; idx += 64) {
        const int ci = idx / ntap;
        const int u  = idx - ci * ntap;
        const int ky = py + 2 * (u / nkx);
        const int kx = px + 2 * (u % nkx);
        float v = rintf(w[(size_t)(ci * Cout + co) * 25 + ky * 5 + kx]);
        v = fminf(fmaxf(v, -128.0f), 127.0f);
        s += (int)v;
    }
    #pragma unroll
    for (int off = 32; off > 0; off >>= 1)
        s += __shfl_down(s, off, 64);
    if (threadIdx.x == 0) ts[i] = s;
}

// shift tables
__device__ __constant__ const int S_NT[9]     = {1,2,2,2,4,4,2,4,4};
__device__ __constant__ const int S_TAP[9][4] = {
    {0,0,0,0},{1,9,0,0},{2,10,0,0},{3,15,0,0},
    {4,11,16,21},{5,12,17,22},{6,18,0,0},{7,13,19,23},{8,14,20,24}};
__device__ __constant__ const int S_PAR[9][4] = {
    {0,0,0,0},{0,1,0,0},{0,1,0,0},{0,2,0,0},
    {0,1,2,3},{0,1,2,3},{0,2,0,0},{0,1,2,3},{0,1,2,3}};

// Layers 1-3. 512 threads = 8 waves; each wave one 32-quad m-subtile (2 quad
// rows x 16 cols); block tile 16x16 quads x 32 co x 4 parities. KC=64 staged.
template<int KC>
__global__ __launch_bounds__(512)
void deconv_i8(const signed char* __restrict__ xin, const signed char* __restrict__ wpk,
               const float* __restrict__ bias, const float* __restrict__ muls,
               const int* __restrict__ tsum,
               const float* __restrict__ relus, const int* __restrict__ dvds,
               const int* __restrict__ bitsp,
               int layer, int Cin, int Cout, int NT, int Hq, int Wq,
               signed char* __restrict__ outp) {
    __shared__ __align__(16) signed char xs[324 * KC];

    const int tid  = threadIdx.x;
    const int lane = tid & 63;
    const int wid  = tid >> 6;               // 0..7 = m-subtile
    const int qx0  = blockIdx.y * 16;
    const int qy0  = blockIdx.z * 16;
    const int nb   = blockIdx.x;
    const int n0   = nb * 32;

    int16v acc[4];
    #pragma unroll
    for (int p = 0; p < 4; ++p)
        #pragma unroll
        for (int e = 0; e < 16; ++e) acc[p][e] = 0;

    const int half   = lane >> 5;
    const int rowbit = (lane >> 4) & 1;
    const int col    = lane & 15;
    const int p0 = (wid * 2 + rowbit) * 18 + col;

    for (int ck = 0; ck < Cin; ck += KC) {
        __syncthreads();
        constexpr int NG = KC / 16;
        for (int i = tid; i < 324 * NG; i += 512) {
            int p = i / NG;
            int g = i - p * NG;
            int rr = p / 18, cc = p - rr * 18;
            int y = qy0 - 1 + rr, x = qx0 - 1 + cc;
            int4v v = {(int)0x80808080, (int)0x80808080, (int)0x80808080, (int)0x80808080};
            if ((unsigned)y < (unsigned)Hq && (unsigned)x < (unsigned)Wq)
                v = *(const int4v*)&xin[((size_t)y * Wq + x) * Cin + ck + g * 16];
            *(int4v*)&xs[(g * 324 + p) * 16] = v;
        }
        __syncthreads();

        for (int qs = 0; qs < KC / 32; ++qs) {
            const signed char* wq =
                wpk + (((size_t)((ck >> 5) + qs) * NT + nb) * 25) * 1024 + (lane << 4);
            const int abase = ((qs * 2 + half) * 324) * 16;

            #pragma unroll
            for (int s9 = 0; s9 < 9; ++s9) {
                const int dy = s9 / 3, dx = s9 % 3;
                int4v a = *(const int4v*)&xs[abase + (p0 + dy * 18 + dx) * 16];
                #pragma unroll
                for (int u = 0; u < 4; ++u) {
                    if (u < S_NT[s9]) {
                        const int t = S_TAP[s9][u];
                        const int p = S_PAR[s9][u];
                        int4v b = *(const int4v*)&wq[t * 1024];
                        acc[p] = __builtin_amdgcn_mfma_i32_32x32x32_i8(a, b, acc[p], 0, 0, 0);
                    }
                }
            }
        }
    }

    // ----- quant epilogue (exact fp32 op sequence) ---------------------------
    const int dv = dvds[layer];
    float add1 = ldexpf(1.0f, dv - 10);
    float inv1 = ldexpf(1.0f, -(dv - 9));
    const float relu = relus[layer];
    const int sk = (layer == 1) ? 4 : 3;
    const float bitsv = ldexpf(1.0f, bitsp[0]) - 1.0f;
    float clp, scl;
    {
        #pragma clang fp contract(off)
        clp = rintf(bitsv / relu * 33554432.0f);
        scl = floorf((relu + ldexpf(1.0f, sk - 1)) * ldexpf(1.0f, -sk));
    }
    float add2 = ldexpf(1.0f, 24 - sk);
    float inv2 = ldexpf(1.0f, -(25 - sk));

    const int co = n0 + (lane & 31);
    float bq = rintf(bias[co]);
    float mm = muls[co];
    int fullp[4];
    #pragma unroll
    for (int p = 0; p < 4; ++p) fullp[p] = tsum[p * Cout + co];

    const int Wout = Wq * 2;

    #pragma unroll
    for (int p = 0; p < 4; ++p) {
        const int py = p >> 1, px = p & 1;
        #pragma unroll
        for (int reg = 0; reg < 16; ++reg) {
            const int mrow = (reg & 3) + 8 * (reg >> 2) + 4 * (lane >> 5);
            const int qy = qy0 + wid * 2 + (mrow >> 4);
            const int qx = qx0 + (mrow & 15);
            float v = (float)(acc[p][reg] + 128 * fullp[p]);
            {
                #pragma clang fp contract(off)
                v = (v + bq) * mm;
                v = floorf((v + add1) * inv1);
                v = fminf(fmaxf(v, 0.0f), clp);
                v = floorf((v * scl + add2) * inv2);
            }
            const int oy = 2 * qy + py, ox = 2 * qx + px;
            outp[((size_t)oy * Wout + ox) * Cout + co] = (signed char)((int)v - 128);
        }
    }
}

// Final layer: N = (parity,co) columns (c = p*8+co), 1 MFMA per shift.
__global__ __launch_bounds__(512)
void deconv_i8_final(const signed char* __restrict__ xin, const signed char* __restrict__ wpk,
                     const float* __restrict__ bias, const float* __restrict__ muls,
                     const int* __restrict__ tsum, const int* __restrict__ dvds,
                     int Cin, int Hq, int Wq, float* __restrict__ outp) {
    constexpr int KC = 64;
    __shared__ __align__(16) signed char xs[324 * KC];

    const int tid  = threadIdx.x;
    const int lane = tid & 63;
    const int wid  = tid >> 6;
    const int qx0  = blockIdx.y * 16;
    const int qy0  = blockIdx.z * 16;

    int16v acc;
    #pragma unroll
    for (int e = 0; e < 16; ++e) acc[e] = 0;

    const int half   = lane >> 5;
    const int rowbit = (lane >> 4) & 1;
    const int col16  = lane & 15;
    const int p0 = (wid * 2 + rowbit) * 18 + col16;

    for (int ck = 0; ck < Cin; ck += KC) {
        __syncthreads();
        constexpr int NG = KC / 16;
        for (int i = tid; i < 324 * NG; i += 512) {
            int p = i / NG;
            int g = i - p * NG;
            int rr = p / 18, cc = p - rr * 18;
            int y = qy0 - 1 + rr, x = qx0 - 1 + cc;
            int4v v = {(int)0x80808080, (int)0x80808080, (int)0x80808080, (int)0x80808080};
            if ((unsigned)y < (unsigned)Hq && (unsigned)x < (unsigned)Wq)
                v = *(const int4v*)&xin[((size_t)y * Wq + x) * Cin + ck + g * 16];
            *(int4v*)&xs[(g * 324 + p) * 16] = v;
        }
        __syncthreads();

        for (int qs = 0; qs < KC / 32; ++qs) {
            const signed char* wq =
                wpk + ((size_t)((ck >> 5) + qs) * 9) * 1024 + (lane << 4);
            const int abase = ((qs * 2 + half) * 324) * 16;
            #pragma unroll
            for (int s9 = 0; s9 < 9; ++s9) {
                const int dy = s9 / 3, dx = s9 % 3;
                int4v a = *(const int4v*)&xs[abase + (p0 + dy * 18 + dx) * 16];
                int4v b = *(const int4v*)&wq[s9 * 1024];
                acc = __builtin_amdgcn_mfma_i32_32x32x32_i8(a, b, acc, 0, 0, 0);
            }
        }
    }

    const int dv = dvds[3];
    const float add1 = ldexpf(1.0f, dv - 9);
    const float inv1 = ldexpf(1.0f, -(dv - 8));

    const int col = lane & 31;
    const int co = col & 7;
    const int p  = col >> 3;
    const int py = p >> 1, px = p & 1;
    const bool valid = (co < 3);
    float bq = 0.f, mm = 0.f;
    int fp = 0;
    if (valid) { bq = rintf(bias[co]); mm = muls[co]; fp = tsum[p * 3 + co]; }

    const int Wout = Wq * 2, Hout = Hq * 2;
    #pragma unroll
    for (int reg = 0; reg < 16; ++reg) {
        const int mrow = (reg & 3) + 8 * (reg >> 2) + 4 * (lane >> 5);
        const int qy = qy0 + wid * 2 + (mrow >> 4);
        const int qx = qx0 + (mrow & 15);
        float v = (float)(acc[reg] + 128 * fp);
        {
            #pragma clang fp contract(off)
            v = (v + bq) * mm;
            v = floorf((v + add1) * inv1);
            v = v / 255.0f;
        }
        if (valid) {
            const int oy = 2 * qy + py, ox = 2 * qx + px;
            outp[((size_t)co * Hout + oy) * Wout + ox] = v;
        }
    }
}

extern "C" void kernel_launch(void* const* d_in, const int* in_sizes, int n_in,
                              void* d_out, int out_size, void* d_ws, size_t ws_size,
                              hipStream_t stream) {
    const float* x  = (const float*)d_in[0];
    const float* w1 = (const float*)d_in[1];
    const float* b1 = (const float*)d_in[2];
    const float* w2 = (const float*)d_in[3];
    const float* b2 = (const float*)d_in[4];
    const float* w3 = (const float*)d_in[5];
    const float* b3 = (const float*)d_in[6];
    const float* w4 = (const float*)d_in[7];
    const float* b4 = (const float*)d_in[8];
    const float* m0 = (const float*)d_in[9];
    const float* m1 = (const float*)d_in[10];
    const float* m2 = (const float*)d_in[11];
    const float* m3 = (const float*)d_in[12];
    const float* relus = (const float*)d_in[13];
    const int* dvds = (const int*)d_in[14];
    const int* bitsp = (const int*)d_in[15];

    signed char* wsb = (signed char*)d_ws;
    size_t o = 0;
    signed char* wpk1 = wsb + o; o += (size_t)10 * 6 * 25 * 1024;  // 1,536,000
    signed char* wpk2 = wsb + o; o += (size_t)6 * 6 * 25 * 1024;   //   921,600
    signed char* wpk3 = wsb + o; o += (size_t)6 * 6 * 25 * 1024;
    signed char* wpk4 = wsb + o; o += (size_t)6 * 9 * 1024;        //    55,296
    int* ts1 = (int*)(wsb + o); o += 4 * 192 * 4;
    int* ts2 = (int*)(wsb + o); o += 4 * 192 * 4;
    int* ts3 = (int*)(wsb + o); o += 4 * 192 * 4;
    int* ts4 = (int*)(wsb + o); o += 4 * 4 * 4;
    o = (o + 15) & ~(size_t)15;
    signed char* xh = wsb + o; o += (size_t)48 * 48 * 320;
    signed char* a1 = wsb + o; o += (size_t)96 * 96 * 192;
    signed char* a2 = wsb + o; o += (size_t)192 * 192 * 192;
    signed char* a3 = wsb + o; o += (size_t)384 * 384 * 192;

    convert_x_t<<<dim3(36, 5), 256, 0, stream>>>(x, xh, 320, 48 * 48);
    pack_w_i8<<<(10 * 6 * 25 * 1024 + 255) / 256, 256, 0, stream>>>(w1, wpk1, 192, 6, 10);
    pack_w_i8<<<(6 * 6 * 25 * 1024 + 255) / 256, 256, 0, stream>>>(w2, wpk2, 192, 6, 6);
    pack_w_i8<<<(6 * 6 * 25 * 1024 + 255) / 256, 256, 0, stream>>>(w3, wpk3, 192, 6, 6);
    pack_w4_i8<<<(6 * 9 * 1024 + 255) / 256, 256, 0, stream>>>(w4, wpk4);
    tap_sums<<<4 * 192, 64, 0, stream>>>(w1, ts1, 320, 192);
    tap_sums<<<4 * 192, 64, 0, stream>>>(w2, ts2, 192, 192);
    tap_sums<<<4 * 192, 64, 0, stream>>>(w3, ts3, 192, 192);
    tap_sums<<<4 * 3, 64, 0, stream>>>(w4, ts4, 192, 3);

    // layer 1: 48x48x320 -> 96x96x192
    deconv_i8<64><<<dim3(6, 3, 3), 512, 0, stream>>>(
        xh, wpk1, b1, m0, ts1, relus, dvds, bitsp, 0, 320, 192, 6, 48, 48, a1);
    // layer 2: 96x96x192 -> 192x192x192
    deconv_i8<64><<<dim3(6, 6, 6), 512, 0, stream>>>(
        a1, wpk2, b2, m1, ts2, relus, dvds, bitsp, 1, 192, 192, 6, 96, 96, a2);
    // layer 3: 192x192x192 -> 384x384x192
    deconv_i8<64><<<dim3(6, 12, 12), 512, 0, stream>>>(
        a2, wpk3, b3, m2, ts3, relus, dvds, bitsp, 2, 192, 192, 6, 192, 192, a3);
    // layer 4: 384x384x192 -> 3x768x768 (final, f32 NCHW, /255)
    deconv_i8_final<<<dim3(1, 24, 24), 512, 0, stream>>>(
        a3, wpk4, b4, m3, ts4, dvds, 192, 384, 384, (float*)d_out);
}

// Round 6
// 261.972 us; speedup vs baseline: 5.2816x; 1.1927x over previous
//
#include <hip/hip_runtime.h>
#include <cmath>

// ---------------------------------------------------------------------------
// g_s: 4x chained conv_transpose2d(k=5,s=2,p=2,op=1) + integer quant epilogue.
// Hermite: sum_j floor((round(w)+j)/split) == round(w) -> one conv per layer.
// Exact i8: weights round(w) in [-127,127]; activations (x-128) in i8; OOB
// halo = -128 so conv_i8 = conv_ref(x) - 128*tapsum[parity][co] (exact i32).
// MFMA v_mfma_i32_32x32x32_i8. v3: B staged through LDS (8x TCP cut — B-frag
// reuse was 1, all waves in a block read identical B), coalesced weight pack.
// ---------------------------------------------------------------------------

typedef int int4v  __attribute__((ext_vector_type(4)));
typedef int int16v __attribute__((ext_vector_type(16)));

// tap id -> (ky,kx). Taps 0-8: EE; 9-14: EO; 15-20: OE; 21-24: OO.
__device__ __forceinline__ void tap_to_k(int t, int& ky, int& kx) {
    if (t < 9)       { int dy = t/3,  dx = t%3;                   ky = 4-2*dy; kx = 4-2*dx; }
    else if (t < 15) { int u = t-9;   int dy = u/2, dx = 1+(u&1);  ky = 4-2*dy; kx = 5-2*dx; }
    else if (t < 21) { int u = t-15;  int dy = 1+u/3, dx = u%3;    ky = 5-2*dy; kx = 4-2*dx; }
    else             { int u = t-21;  int dy = 1+u/2, dx = 1+(u&1); ky = 5-2*dy; kx = 5-2*dx; }
}

// f32 NCHW -> i8 (x-128) NHWC via LDS transpose (both sides coalesced)
__global__ __launch_bounds__(256)
void convert_x_t(const float* __restrict__ x, signed char* __restrict__ xh,
                 int C, int HW) {
    __shared__ float t[64][65];
    const int p0 = blockIdx.x * 64;
    const int c0 = blockIdx.y * 64;
    const int pL = threadIdx.x & 63;
    const int r0 = threadIdx.x >> 6;  // 0..3
    #pragma unroll
    for (int k = 0; k < 16; ++k) {
        int ciL = r0 * 16 + k;
        t[ciL][pL] = x[(size_t)(c0 + ciL) * HW + p0 + pL];
    }
    __syncthreads();
    #pragma unroll
    for (int k = 0; k < 16; ++k) {
        int pL2 = r0 * 16 + k;
        xh[(size_t)(p0 + pL2) * C + c0 + pL] = (signed char)((int)t[pL][pL2] - 128);
    }
}

// Coalesced pack for layers 1-3: one thread per (ci,co), reads 25 contiguous
// floats, writes 25 scattered bytes into B-fragment order:
// byte addr = ((qs*NT + nb)*25 + t)*1024 + lane*16 + j
__global__ __launch_bounds__(256)
void pack3(const float* __restrict__ w1, const float* __restrict__ w2,
           const float* __restrict__ w3,
           signed char* __restrict__ p1, signed char* __restrict__ p2,
           signed char* __restrict__ p3) {
    const int layer = blockIdx.y;
    const float* w = (layer == 0) ? w1 : (layer == 1) ? w2 : w3;
    signed char* out = (layer == 0) ? p1 : (layer == 1) ? p2 : p3;
    const int Cin = (layer == 0) ? 320 : 192;
    const int Cout = 192, NT = 6;
    int idx = blockIdx.x * 256 + threadIdx.x;
    if (idx >= Cin * Cout) return;
    const int co = idx % Cout, ci = idx / Cout;
    const float* wr = w + (size_t)(ci * Cout + co) * 25;
    float v[25];
    #pragma unroll
    for (int k = 0; k < 25; ++k) {
        float t = rintf(wr[k]);
        v[k] = fminf(fmaxf(t, -128.0f), 127.0f);
    }
    const int qs = ci >> 5, half = (ci >> 4) & 1, j = ci & 15;
    const int nb = co >> 5, lane = half * 32 + (co & 31);
    size_t base = ((size_t)(qs * NT + nb) * 25) * 1024 + lane * 16 + j;
    #pragma unroll
    for (int t = 0; t < 25; ++t) {
        int ky, kx; tap_to_k(t, ky, kx);
        out[base + (size_t)t * 1024] = (signed char)(int)v[ky * 5 + kx];
    }
}

// final-layer pack: N-dim = (parity,co): column c = p*8+co (co<3 live).
// byte addr = ((qs*9 + s9)*64 + lane)*16 + j ; value = w[co][ci][tap(s9,p)] or 0
__global__ void pack_w4_i8(const float* __restrict__ w, signed char* __restrict__ wpk) {
    int idx = blockIdx.x * blockDim.x + threadIdx.x;
    if (idx >= 6 * 9 * 64 * 16) return;
    int j    = idx & 15;
    int lane = (idx >> 4) & 63;
    int rem  = idx >> 10;
    int s9   = rem % 9;
    int qs   = rem / 9;
    int col  = lane & 31;
    int co   = col & 7;
    int p    = col >> 3;
    int py = p >> 1, px = p & 1;
    int dy = s9 / 3, dx = s9 % 3;
    int ci = qs * 32 + ((lane >> 5) << 4) + j;
    bool part = (py == 0 || dy >= 1) && (px == 0 || dx >= 1);
    float v = 0.0f;
    if (co < 3 && part) {
        int ky = py ? 5 - 2 * dy : 4 - 2 * dy;
        int kx = px ? 5 - 2 * dx : 4 - 2 * dx;
        v = rintf(w[(size_t)(ci * 3 + co) * 25 + ky * 5 + kx]);
        v = fminf(fmaxf(v, -128.0f), 127.0f);
    }
    wpk[idx] = (signed char)(int)v;
}

// fused tapsum: tapsum[p][co] = sum_{ky%2==py,kx%2==px} sum_ci round(w) (i32)
// grid.y = layer (0..3); one 64-thread block per (p,co); L2-warm after pack3.
__global__ __launch_bounds__(64)
void tap4(const float* __restrict__ w1, const float* __restrict__ w2,
          const float* __restrict__ w3, const float* __restrict__ w4,
          int* __restrict__ t1, int* __restrict__ t2,
          int* __restrict__ t3, int* __restrict__ t4) {
    const int layer = blockIdx.y;
    const float* w = (layer == 0) ? w1 : (layer == 1) ? w2 : (layer == 2) ? w3 : w4;
    int* ts = (layer == 0) ? t1 : (layer == 1) ? t2 : (layer == 2) ? t3 : t4;
    const int Cin = (layer == 0) ? 320 : 192;
    const int Cout = (layer == 3) ? 3 : 192;
    const int i = blockIdx.x;
    if (i >= 4 * Cout) return;
    const int co = i % Cout, p = i / Cout;
    const int py = p >> 1, px = p & 1;
    const int nky = (5 - py + 1) >> 1;
    const int nkx = (5 - px + 1) >> 1;
    const int ntap = nky * nkx;
    int s = 0;
    for (int idx = threadIdx.x; idx < Cin * ntap; idx += 64) {
        const int ci = idx / ntap;
        const int u  = idx - ci * ntap;
        const int ky = py + 2 * (u / nkx);
        const int kx = px + 2 * (u % nkx);
        float v = rintf(w[(size_t)(ci * Cout + co) * 25 + ky * 5 + kx]);
        v = fminf(fmaxf(v, -128.0f), 127.0f);
        s += (int)v;
    }
    #pragma unroll
    for (int off = 32; off > 0; off >>= 1)
        s += __shfl_down(s, off, 64);
    if (threadIdx.x == 0) ts[i] = s;
}

// shift tables
__device__ __constant__ const int S_NT[9]     = {1,2,2,2,4,4,2,4,4};
__device__ __constant__ const int S_TAP[9][4] = {
    {0,0,0,0},{1,9,0,0},{2,10,0,0},{3,15,0,0},
    {4,11,16,21},{5,12,17,22},{6,18,0,0},{7,13,19,23},{8,14,20,24}};
__device__ __constant__ const int S_PAR[9][4] = {
    {0,0,0,0},{0,1,0,0},{0,1,0,0},{0,2,0,0},
    {0,1,2,3},{0,1,2,3},{0,2,0,0},{0,1,2,3},{0,1,2,3}};

// Layers 1-3, v3: MW waves; tile = (MW*2) quad-rows x 16 quad-cols x 32 co.
// KC=32 staged; B slab (25 KB) staged in LDS per k-chunk (8x TCP cut).
// xs pixel stride = 48 B (32 B data + 16 pad) for LDS bank spread.
template<int MW>
__global__ __launch_bounds__(MW * 64)
void deconv_v3(const signed char* __restrict__ xin, const signed char* __restrict__ wpk,
               const float* __restrict__ bias, const float* __restrict__ muls,
               const int* __restrict__ tsum,
               const float* __restrict__ relus, const int* __restrict__ dvds,
               const int* __restrict__ bitsp,
               int layer, int Cin, int Cout, int NT, int Hq, int Wq,
               signed char* __restrict__ outp) {
    constexpr int NROW = MW * 2 + 2;
    constexpr int NPIX = NROW * 18;
    __shared__ __align__(16) signed char xs[NPIX * 48];
    __shared__ __align__(16) signed char bs[25600];

    const int tid  = threadIdx.x;
    const int lane = tid & 63;
    const int wid  = tid >> 6;
    const int qx0  = blockIdx.y * 16;
    const int qy0  = blockIdx.z * (MW * 2);
    const int nb   = blockIdx.x;
    const int n0   = nb * 32;

    int16v acc[4];
    #pragma unroll
    for (int p = 0; p < 4; ++p)
        #pragma unroll
        for (int e = 0; e < 16; ++e) acc[p][e] = 0;

    const int half   = lane >> 5;
    const int rowbit = (lane >> 4) & 1;
    const int col    = lane & 15;
    const int p0 = (wid * 2 + rowbit) * 18 + col;

    for (int ck = 0; ck < Cin; ck += 32) {
        __syncthreads();
        const signed char* wslab = wpk + (size_t)((ck >> 5) * NT + nb) * 25600;
        for (int i = tid; i < NPIX * 2 + 1600; i += MW * 64) {
            if (i < NPIX * 2) {
                int pix = i >> 1, g = i & 1;
                int rr = pix / 18, cc = pix - rr * 18;
                int y = qy0 - 1 + rr, x = qx0 - 1 + cc;
                int4v v = {(int)0x80808080, (int)0x80808080,
                           (int)0x80808080, (int)0x80808080};
                if ((unsigned)y < (unsigned)Hq && (unsigned)x < (unsigned)Wq)
                    v = *(const int4v*)&xin[((size_t)y * Wq + x) * Cin + ck + g * 16];
                *(int4v*)&xs[pix * 48 + g * 16] = v;
            } else {
                int i2 = i - NPIX * 2;
                *(int4v*)&bs[i2 * 16] = *(const int4v*)&wslab[i2 * 16];
            }
        }
        __syncthreads();

        #pragma unroll
        for (int s9 = 0; s9 < 9; ++s9) {
            const int dy = s9 / 3, dx = s9 % 3;
            int4v a = *(const int4v*)&xs[(p0 + dy * 18 + dx) * 48 + half * 16];
            #pragma unroll
            for (int u = 0; u < 4; ++u) {
                if (u < S_NT[s9]) {
                    int4v b = *(const int4v*)&bs[S_TAP[s9][u] * 1024 + lane * 16];
                    acc[S_PAR[s9][u]] =
                        __builtin_amdgcn_mfma_i32_32x32x32_i8(a, b, acc[S_PAR[s9][u]], 0, 0, 0);
                }
            }
        }
    }

    // ----- quant epilogue (exact fp32 op sequence; proven absmax 0.0) --------
    const int dv = dvds[layer];
    float add1 = ldexpf(1.0f, dv - 10);
    float inv1 = ldexpf(1.0f, -(dv - 9));
    const float relu = relus[layer];
    const int sk = (layer == 1) ? 4 : 3;
    const float bitsv = ldexpf(1.0f, bitsp[0]) - 1.0f;
    float clp, scl;
    {
        #pragma clang fp contract(off)
        clp = rintf(bitsv / relu * 33554432.0f);
        scl = floorf((relu + ldexpf(1.0f, sk - 1)) * ldexpf(1.0f, -sk));
    }
    float add2 = ldexpf(1.0f, 24 - sk);
    float inv2 = ldexpf(1.0f, -(25 - sk));

    const int co = n0 + (lane & 31);
    float bq = rintf(bias[co]);
    float mm = muls[co];
    int fullp[4];
    #pragma unroll
    for (int p = 0; p < 4; ++p) fullp[p] = tsum[p * Cout + co];

    const int Wout = Wq * 2;

    #pragma unroll
    for (int p = 0; p < 4; ++p) {
        const int py = p >> 1, px = p & 1;
        #pragma unroll
        for (int reg = 0; reg < 16; ++reg) {
            const int mrow = (reg & 3) + 8 * (reg >> 2) + 4 * (lane >> 5);
            const int qy = qy0 + wid * 2 + (mrow >> 4);
            const int qx = qx0 + (mrow & 15);
            float v = (float)(acc[p][reg] + 128 * fullp[p]);
            {
                #pragma clang fp contract(off)
                v = (v + bq) * mm;
                v = floorf((v + add1) * inv1);
                v = fminf(fmaxf(v, 0.0f), clp);
                v = floorf((v * scl + add2) * inv2);
            }
            const int oy = 2 * qy + py, ox = 2 * qx + px;
            outp[((size_t)oy * Wout + ox) * Cout + co] = (signed char)((int)v - 128);
        }
    }
}

// Final layer v3: N = (parity,co) columns, 1 MFMA per shift, B-LDS staged.
__global__ __launch_bounds__(512)
void deconv_final_v3(const signed char* __restrict__ xin, const signed char* __restrict__ wpk,
                     const float* __restrict__ bias, const float* __restrict__ muls,
                     const int* __restrict__ tsum, const int* __restrict__ dvds,
                     int Cin, int Hq, int Wq, float* __restrict__ outp) {
    constexpr int NPIX = 324;
    __shared__ __align__(16) signed char xs[NPIX * 48];
    __shared__ __align__(16) signed char bs[9216];

    const int tid  = threadIdx.x;
    const int lane = tid & 63;
    const int wid  = tid >> 6;
    const int qx0  = blockIdx.y * 16;
    const int qy0  = blockIdx.z * 16;

    int16v acc;
    #pragma unroll
    for (int e = 0; e < 16; ++e) acc[e] = 0;

    const int half   = lane >> 5;
    const int rowbit = (lane >> 4) & 1;
    const int col16  = lane & 15;
    const int p0 = (wid * 2 + rowbit) * 18 + col16;

    for (int ck = 0; ck < Cin; ck += 32) {
        __syncthreads();
        const signed char* wslab = wpk + (size_t)(ck >> 5) * 9216;
        for (int i = tid; i < NPIX * 2 + 576; i += 512) {
            if (i < NPIX * 2) {
                int pix = i >> 1, g = i & 1;
                int rr = pix / 18, cc = pix - rr * 18;
                int y = qy0 - 1 + rr, x = qx0 - 1 + cc;
                int4v v = {(int)0x80808080, (int)0x80808080,
                           (int)0x80808080, (int)0x80808080};
                if ((unsigned)y < (unsigned)Hq && (unsigned)x < (unsigned)Wq)
                    v = *(const int4v*)&xin[((size_t)y * Wq + x) * Cin + ck + g * 16];
                *(int4v*)&xs[pix * 48 + g * 16] = v;
            } else {
                int i2 = i - NPIX * 2;
                *(int4v*)&bs[i2 * 16] = *(const int4v*)&wslab[i2 * 16];
            }
        }
        __syncthreads();

        #pragma unroll
        for (int s9 = 0; s9 < 9; ++s9) {
            const int dy = s9 / 3, dx = s9 % 3;
            int4v a = *(const int4v*)&xs[(p0 + dy * 18 + dx) * 48 + half * 16];
            int4v b = *(const int4v*)&bs[s9 * 1024 + lane * 16];
            acc = __builtin_amdgcn_mfma_i32_32x32x32_i8(a, b, acc, 0, 0, 0);
        }
    }

    const int dv = dvds[3];
    const float add1 = ldexpf(1.0f, dv - 9);
    const float inv1 = ldexpf(1.0f, -(dv - 8));

    const int col = lane & 31;
    const int co = col & 7;
    const int p  = col >> 3;
    const int py = p >> 1, px = p & 1;
    const bool valid = (co < 3);
    float bq = 0.f, mm = 0.f;
    int fp = 0;
    if (valid) { bq = rintf(bias[co]); mm = muls[co]; fp = tsum[p * 3 + co]; }

    const int Wout = Wq * 2, Hout = Hq * 2;
    #pragma unroll
    for (int reg = 0; reg < 16; ++reg) {
        const int mrow = (reg & 3) + 8 * (reg >> 2) + 4 * (lane >> 5);
        const int qy = qy0 + wid * 2 + (mrow >> 4);
        const int qx = qx0 + (mrow & 15);
        float v = (float)(acc[reg] + 128 * fp);
        {
            #pragma clang fp contract(off)
            v = (v + bq) * mm;
            v = floorf((v + add1) * inv1);
            v = v / 255.0f;
        }
        if (valid) {
            const int oy = 2 * qy + py, ox = 2 * qx + px;
            outp[((size_t)co * Hout + oy) * Wout + ox] = v;
        }
    }
}

extern "C" void kernel_launch(void* const* d_in, const int* in_sizes, int n_in,
                              void* d_out, int out_size, void* d_ws, size_t ws_size,
                              hipStream_t stream) {
    const float* x  = (const float*)d_in[0];
    const float* w1 = (const float*)d_in[1];
    const float* b1 = (const float*)d_in[2];
    const float* w2 = (const float*)d_in[3];
    const float* b2 = (const float*)d_in[4];
    const float* w3 = (const float*)d_in[5];
    const float* b3 = (const float*)d_in[6];
    const float* w4 = (const float*)d_in[7];
    const float* b4 = (const float*)d_in[8];
    const float* m0 = (const float*)d_in[9];
    const float* m1 = (const float*)d_in[10];
    const float* m2 = (const float*)d_in[11];
    const float* m3 = (const float*)d_in[12];
    const float* relus = (const float*)d_in[13];
    const int* dvds = (const int*)d_in[14];
    const int* bitsp = (const int*)d_in[15];

    signed char* wsb = (signed char*)d_ws;
    size_t o = 0;
    signed char* wpk1 = wsb + o; o += (size_t)10 * 6 * 25600;   // 1,536,000
    signed char* wpk2 = wsb + o; o += (size_t)6 * 6 * 25600;    //   921,600
    signed char* wpk3 = wsb + o; o += (size_t)6 * 6 * 25600;
    signed char* wpk4 = wsb + o; o += (size_t)6 * 9216;         //    55,296
    int* ts1 = (int*)(wsb + o); o += 4 * 192 * 4;
    int* ts2 = (int*)(wsb + o); o += 4 * 192 * 4;
    int* ts3 = (int*)(wsb + o); o += 4 * 192 * 4;
    int* ts4 = (int*)(wsb + o); o += 4 * 4 * 4;
    o = (o + 15) & ~(size_t)15;
    signed char* xh = wsb + o; o += (size_t)48 * 48 * 320;
    signed char* a1 = wsb + o; o += (size_t)96 * 96 * 192;
    signed char* a2 = wsb + o; o += (size_t)192 * 192 * 192;
    signed char* a3 = wsb + o; o += (size_t)384 * 384 * 192;

    convert_x_t<<<dim3(36, 5), 256, 0, stream>>>(x, xh, 320, 48 * 48);
    pack3<<<dim3(240, 3), 256, 0, stream>>>(w1, w2, w3, wpk1, wpk2, wpk3);
    pack_w4_i8<<<(6 * 9 * 1024 + 255) / 256, 256, 0, stream>>>(w4, wpk4);
    tap4<<<dim3(768, 4), 64, 0, stream>>>(w1, w2, w3, w4, ts1, ts2, ts3, ts4);

    // layer 1: 48x48x320 -> 96x96x192   (MW=4: 8x16-quad tiles, 108 blocks)
    deconv_v3<4><<<dim3(6, 3, 6), 256, 0, stream>>>(
        xh, wpk1, b1, m0, ts1, relus, dvds, bitsp, 0, 320, 192, 6, 48, 48, a1);
    // layer 2: 96x96x192 -> 192x192x192 (MW=8: 16x16 tiles, 216 blocks)
    deconv_v3<8><<<dim3(6, 6, 6), 512, 0, stream>>>(
        a1, wpk2, b2, m1, ts2, relus, dvds, bitsp, 1, 192, 192, 6, 96, 96, a2);
    // layer 3: 192x192x192 -> 384x384x192 (864 blocks)
    deconv_v3<8><<<dim3(6, 12, 12), 512, 0, stream>>>(
        a2, wpk3, b3, m2, ts3, relus, dvds, bitsp, 2, 192, 192, 6, 192, 192, a3);
    // layer 4: 384x384x192 -> 3x768x768 (final, f32 NCHW, /255; 576 blocks)
    deconv_final_v3<<<dim3(1, 24, 24), 512, 0, stream>>>(
        a3, wpk4, b4, m3, ts4, dvds, 192, 384, 384, (float*)d_out);
}